// Round 2
// baseline (847.324 us; speedup 1.0000x reference)
//
#include <hip/hip_runtime.h>

#define HID 16
#define ODIM 64
#define IDIM 512

// ------------------------------------------- per-node in-degree histogram
// 3.2M atomics over 100k counters = ~32/counter, 2 per 64B line per ~wave: cheap.
__global__ __launch_bounds__(256) void k_hist(const int* __restrict__ dst,
                                              int* __restrict__ cnt, int ne) {
    int stride = gridDim.x * blockDim.x;
    for (int e = blockIdx.x * blockDim.x + threadIdx.x; e < ne; e += stride)
        atomicAdd(&cnt[dst[e]], 1);
}

// ------------------------------------------- two-level exclusive scan of cnt
__global__ __launch_bounds__(256) void k_scan1(const int* __restrict__ cnt,
                                               int* __restrict__ row_start,
                                               int* __restrict__ bsum, int n) {
    __shared__ int s[256];
    int t = threadIdx.x;
    int node = blockIdx.x * 256 + t;
    int c = (node < n) ? cnt[node] : 0;
    s[t] = c;
    __syncthreads();
    for (int off = 1; off < 256; off <<= 1) {
        int u = (t >= off) ? s[t - off] : 0;
        __syncthreads();
        s[t] += u;
        __syncthreads();
    }
    if (node < n) row_start[node] = s[t] - c;   // block-local exclusive
    if (t == 255) bsum[blockIdx.x] = s[255];
}

__global__ __launch_bounds__(512) void k_scan2(const int* __restrict__ bsum,
                                               int* __restrict__ bbase, int nbk) {
    __shared__ int s[512];
    int t = threadIdx.x;
    int v = (t < nbk) ? bsum[t] : 0;
    s[t] = v;
    __syncthreads();
    for (int off = 1; off < 512; off <<= 1) {
        int u = (t >= off) ? s[t - off] : 0;
        __syncthreads();
        s[t] += u;
        __syncthreads();
    }
    if (t < nbk) bbase[t] = s[t] - v;
}

__global__ __launch_bounds__(256) void k_scan3(int* __restrict__ row_start,
                                               const int* __restrict__ bbase,
                                               int* __restrict__ cur, int n) {
    int node = blockIdx.x * 256 + threadIdx.x;
    if (node < n) {
        int r = row_start[node] + bbase[blockIdx.x];
        row_start[node] = r;
        cur[node] = r;
    }
}

// ------------------------------------------- direct CSR scatter (counting sort)
// pos atomics: 32 hits/counter, spread over 100k counters -> no hot lines.
// Row-internal order nondeterministic: fp32 reorder error ~1e-6 << tolerance.
__global__ __launch_bounds__(256) void k_scat(const int* __restrict__ src,
                                              const int* __restrict__ dst,
                                              int* __restrict__ cur,
                                              int* __restrict__ csr_src, int ne) {
    int stride = gridDim.x * blockDim.x;
    for (int e = blockIdx.x * blockDim.x + threadIdx.x; e < ne; e += stride) {
        int s = src[e];
        int p = atomicAdd(&cur[dst[e]], 1);
        csr_src[p] = s;
    }
}

// ------------------------------------------------- layer1 projection: X @ W1
// W1 read with wave-uniform float4 indices -> s_load broadcast (scalar pipe).
// unroll 4 keeps 4 streaming X float4-loads in flight (only ~1.5 waves/SIMD here).
__device__ __forceinline__ void fmaq(float4& a, float s, float4 w) {
    a.x = fmaf(s, w.x, a.x);
    a.y = fmaf(s, w.y, a.y);
    a.z = fmaf(s, w.z, a.z);
    a.w = fmaf(s, w.w, a.w);
}

__global__ __launch_bounds__(256) void k_proj1(const float* __restrict__ X,
                                               const float* __restrict__ W1,
                                               const int* __restrict__ cnt,
                                               float* __restrict__ hs1, int n) {
    int i = blockIdx.x * 256 + threadIdx.x;
    if (i >= n) return;

    const float4* __restrict__ xr = (const float4*)(X + (size_t)i * IDIM);
    const float4* __restrict__ W4 = (const float4*)W1;  // row k = W4[k*4 .. k*4+3]
    float4 a0 = make_float4(0.f, 0.f, 0.f, 0.f), a1 = a0, a2 = a0, a3 = a0;

#pragma unroll 4
    for (int k4 = 0; k4 < IDIM / 4; ++k4) {
        float4 x = xr[k4];
        const float4* w = W4 + k4 * 16;   // 4 rows x 4 float4, wave-uniform address
        fmaq(a0, x.x, w[0]);  fmaq(a1, x.x, w[1]);  fmaq(a2, x.x, w[2]);  fmaq(a3, x.x, w[3]);
        fmaq(a0, x.y, w[4]);  fmaq(a1, x.y, w[5]);  fmaq(a2, x.y, w[6]);  fmaq(a3, x.y, w[7]);
        fmaq(a0, x.z, w[8]);  fmaq(a1, x.z, w[9]);  fmaq(a2, x.z, w[10]); fmaq(a3, x.z, w[11]);
        fmaq(a0, x.w, w[12]); fmaq(a1, x.w, w[13]); fmaq(a2, x.w, w[14]); fmaq(a3, x.w, w[15]);
    }

    float di = rsqrtf((float)(cnt[i] + 1));
    a0.x *= di; a0.y *= di; a0.z *= di; a0.w *= di;
    a1.x *= di; a1.y *= di; a1.z *= di; a1.w *= di;
    a2.x *= di; a2.y *= di; a2.z *= di; a2.w *= di;
    a3.x *= di; a3.y *= di; a3.z *= di; a3.w *= di;
    float4* h4 = (float4*)(hs1 + (size_t)i * HID);
    h4[0] = a0; h4[1] = a1; h4[2] = a2; h4[3] = a3;
}

// ------------------------------------------- atomic-free aggregation via CSR
// 8 independent gathers in flight per iteration, 2 accumulator chains.
__device__ __forceinline__ void acc4(float4& a, float4 v) {
    a.x += v.x; a.y += v.y; a.z += v.z; a.w += v.w;
}

__device__ __forceinline__ float4 gacc(int rs, int c, int q,
                                       const int* __restrict__ csr_src,
                                       const float4* __restrict__ h4,
                                       float4 acc) {
    float4 acc2 = make_float4(0.f, 0.f, 0.f, 0.f);
    int k = 0;
    int head = (-rs) & 3;            // peel to 16B-aligned csr_src
    if (head > c) head = c;
    for (; k < head; ++k)
        acc4(acc, h4[(size_t)csr_src[rs + k] * 4 + q]);
    for (; k + 7 < c; k += 8) {
        int4 s0 = *(const int4*)(csr_src + rs + k);
        int4 s1 = *(const int4*)(csr_src + rs + k + 4);
        float4 v0 = h4[(size_t)s0.x * 4 + q];
        float4 v1 = h4[(size_t)s0.y * 4 + q];
        float4 v2 = h4[(size_t)s0.z * 4 + q];
        float4 v3 = h4[(size_t)s0.w * 4 + q];
        float4 w0 = h4[(size_t)s1.x * 4 + q];
        float4 w1 = h4[(size_t)s1.y * 4 + q];
        float4 w2 = h4[(size_t)s1.z * 4 + q];
        float4 w3 = h4[(size_t)s1.w * 4 + q];
        acc4(acc, v0);  acc4(acc2, w0);
        acc4(acc, v1);  acc4(acc2, w1);
        acc4(acc, v2);  acc4(acc2, w2);
        acc4(acc, v3);  acc4(acc2, w3);
    }
    for (; k + 3 < c; k += 4) {
        int4 s = *(const int4*)(csr_src + rs + k);
        acc4(acc, h4[(size_t)s.x * 4 + q]);
        acc4(acc2, h4[(size_t)s.y * 4 + q]);
        acc4(acc, h4[(size_t)s.z * 4 + q]);
        acc4(acc2, h4[(size_t)s.w * 4 + q]);
    }
    for (; k < c; ++k)
        acc4(acc, h4[(size_t)csr_src[rs + k] * 4 + q]);
    acc4(acc, acc2);
    return acc;
}

// gather + fused layer-1 finalize: h2 = relu(di*agg + b1) * di
__global__ __launch_bounds__(256) void k_gather_mid(const int* __restrict__ row_start,
                                                    const int* __restrict__ cnt,
                                                    const int* __restrict__ csr_src,
                                                    const float* __restrict__ hs,
                                                    const float* __restrict__ b1,
                                                    float* __restrict__ outbuf, int n) {
    int tid = blockIdx.x * blockDim.x + threadIdx.x;
    int i = tid >> 2;
    int q = tid & 3;
    if (i >= n) return;
    const float4* h4 = (const float4*)hs;
    int rs = row_start[i];
    int c = cnt[i];
    float4 acc = gacc(rs, c, q, csr_src, h4, h4[(size_t)i * 4 + q]);  // self loop as init
    float di = rsqrtf((float)(c + 1));
    float4 b = ((const float4*)b1)[q];
    float4 r;
    r.x = fmaxf(fmaf(di, acc.x, b.x), 0.f) * di;
    r.y = fmaxf(fmaf(di, acc.y, b.y), 0.f) * di;
    r.z = fmaxf(fmaf(di, acc.z, b.z), 0.f) * di;
    r.w = fmaxf(fmaf(di, acc.w, b.w), 0.f) * di;
    ((float4*)outbuf)[(size_t)i * 4 + q] = r;
}

// plain gather (layer 2 aggregation)
__global__ __launch_bounds__(256) void k_gather(const int* __restrict__ row_start,
                                                const int* __restrict__ cnt,
                                                const int* __restrict__ csr_src,
                                                const float* __restrict__ hs,
                                                float* __restrict__ agg, int n) {
    int tid = blockIdx.x * blockDim.x + threadIdx.x;
    int i = tid >> 2;
    int q = tid & 3;
    if (i >= n) return;
    const float4* h4 = (const float4*)hs;
    int rs = row_start[i];
    int c = cnt[i];
    float4 acc = gacc(rs, c, q, csr_src, h4, h4[(size_t)i * 4 + q]);
    ((float4*)agg)[(size_t)i * 4 + q] = acc;
}

// ----------------------------------------------- output projection g @ W2 + b
// Each thread owns ONE W2 column (16 VGPRs), amortized over 4 nodes.
__global__ __launch_bounds__(256) void k_out(const int* __restrict__ cnt,
                                             const float* __restrict__ agg2,
                                             const float* __restrict__ W2,
                                             const float* __restrict__ b2,
                                             float* __restrict__ out, int n) {
    __shared__ float Ws[HID * ODIM];
    __shared__ float bs[ODIM];
    int t = threadIdx.x;
    for (int u = t; u < HID * ODIM; u += 256) Ws[u] = W2[u];
    if (t < ODIM) bs[t] = b2[t];
    __syncthreads();

    int j = t & 63;            // output column
    int slot = t >> 6;         // 0..3 (== wave id)
    int i0 = blockIdx.x * 16 + slot * 4;

    float wc[HID];
#pragma unroll
    for (int k = 0; k < HID; ++k) wc[k] = Ws[k * ODIM + j];
    float bj = bs[j];

    const float4* g4 = (const float4*)agg2;
#pragma unroll
    for (int u = 0; u < 4; ++u) {
        int i = i0 + u;
        if (i < n) {
            float4 g0 = g4[(size_t)i * 4 + 0];
            float4 g1 = g4[(size_t)i * 4 + 1];
            float4 g2 = g4[(size_t)i * 4 + 2];
            float4 g3 = g4[(size_t)i * 4 + 3];
            float acc = g0.x * wc[0]  + g0.y * wc[1]  + g0.z * wc[2]  + g0.w * wc[3]
                      + g1.x * wc[4]  + g1.y * wc[5]  + g1.z * wc[6]  + g1.w * wc[7]
                      + g2.x * wc[8]  + g2.y * wc[9]  + g2.z * wc[10] + g2.w * wc[11]
                      + g3.x * wc[12] + g3.y * wc[13] + g3.z * wc[14] + g3.w * wc[15];
            float di = rsqrtf((float)(cnt[i] + 1));
            out[(size_t)i * ODIM + j] = fmaf(di, acc, bj);
        }
    }
}

// ---------------------------------------------------------------------- launch
extern "C" void kernel_launch(void* const* d_in, const int* in_sizes, int n_in,
                              void* d_out, int out_size, void* d_ws, size_t ws_size,
                              hipStream_t stream) {
    const int* E = (const int*)d_in[1];
    const float* X = (const float*)d_in[2];
    const float* W1 = (const float*)d_in[3];
    const float* b1 = (const float*)d_in[4];
    const float* W2 = (const float*)d_in[5];
    const float* b2 = (const float*)d_in[6];
    float* out = (float*)d_out;

    const int n = in_sizes[0];       // 100000
    const int ne = in_sizes[1] / 2;  // 3200000
    const int* src = E;
    const int* dst = E + ne;
    const int nbk = (n + 255) >> 8;  // 391 scan blocks

    // workspace layout (bytes):
    //   bsum      @ 0      (2 KB)
    //   bbase     @ 8 KB   (2 KB)
    //   cnt       @ 1 MB   (400 KB)
    //   row_start @ 2 MB   (400 KB)
    //   cur       @ 2.5 MB (400 KB)
    //   B1        @ 3 MB   (6.4 MB)
    //   B2        @ 10 MB  (6.4 MB)
    //   csr_src   @ 17 MB  (12.8 MB)   -> total 29.8 MB
    char* ws = (char*)d_ws;
    int* bsum = (int*)ws;
    int* bbase = (int*)(ws + (8u << 10));
    int* cnt = (int*)(ws + (1u << 20));
    int* row_start = (int*)(ws + (2u << 20));
    int* cur = (int*)(ws + (2u << 20) + (512u << 10));
    float* B1 = (float*)(ws + (3u << 20));
    float* B2 = (float*)(ws + (10u << 20));
    int* csr_src = (int*)(ws + (17u << 20));

    hipMemsetAsync(cnt, 0, n * sizeof(int), stream);
    k_hist<<<2048, 256, 0, stream>>>(dst, cnt, ne);
    k_scan1<<<nbk, 256, 0, stream>>>(cnt, row_start, bsum, n);
    k_scan2<<<1, 512, 0, stream>>>(bsum, bbase, nbk);
    k_scan3<<<nbk, 256, 0, stream>>>(row_start, bbase, cur, n);
    k_scat<<<2048, 256, 0, stream>>>(src, dst, cur, csr_src, ne);

    k_proj1<<<(n + 255) / 256, 256, 0, stream>>>(X, W1, cnt, B1, n);
    k_gather_mid<<<(n * 4 + 255) / 256, 256, 0, stream>>>(row_start, cnt, csr_src, B1, b1, B2, n);
    k_gather<<<(n * 4 + 255) / 256, 256, 0, stream>>>(row_start, cnt, csr_src, B2, B1, n);
    k_out<<<(n + 15) / 16, 256, 0, stream>>>(cnt, B1, W2, b2, out, n);
}

// Round 3
// 509.445 us; speedup vs baseline: 1.6632x; 1.6632x over previous
//
#include <hip/hip_runtime.h>

#define HID 16
#define ODIM 64
#define IDIM 512
#define BKB 8          // bucket = 256 nodes (dst >> 8)
#define BKS 256
#define PTILE 4096     // edges per partition tile
#define MAXBE 12288    // LDS staging capacity per bucket (avg 8192, 45 sigma)

// ---------------------------------------------------- bucket histogram (dst>>8)
__global__ __launch_bounds__(256) void k_bhist(const int* __restrict__ dst,
                                               int* __restrict__ bcnt, int ne, int nbk) {
    __shared__ int h[512];
    for (int t = threadIdx.x; t < 512; t += 256) h[t] = 0;
    __syncthreads();
    int stride = gridDim.x * blockDim.x;
    for (int e = blockIdx.x * blockDim.x + threadIdx.x; e < ne; e += stride)
        atomicAdd(&h[dst[e] >> BKB], 1);
    __syncthreads();
    for (int t = threadIdx.x; t < nbk; t += 256)
        if (h[t]) atomicAdd(&bcnt[t], h[t]);
}

// ------------------------------------------------- scan bucket counts (nbk<=512)
__global__ __launch_bounds__(512) void k_bscan(const int* __restrict__ bcnt,
                                               int* __restrict__ bbase,
                                               int* __restrict__ bcur, int nbk) {
    __shared__ int s[512];
    int t = threadIdx.x;
    int v = (t < nbk) ? bcnt[t] : 0;
    s[t] = v;
    __syncthreads();
    for (int off = 1; off < 512; off <<= 1) {
        int u = (t >= off) ? s[t - off] : 0;
        __syncthreads();
        s[t] += u;
        __syncthreads();
    }
    if (t < nbk) { int b = s[t] - v; bbase[t] = b; bcur[t] = b; }
}

// ------------------------------------- partition edges into buckets (staged LDS)
// packed entry: (src << 8) | (dst & 255);  src < 2^17 so fits u32.
__global__ __launch_bounds__(512) void k_part(const int* __restrict__ src,
                                              const int* __restrict__ dst,
                                              int* __restrict__ bcur,
                                              unsigned int* __restrict__ ebuf,
                                              int ne, int nbk) {
    __shared__ int h[512], sc[512], base[512], lcur[512];
    __shared__ unsigned int sval[PTILE];
    __shared__ int saddr[PTILE];
    int e0 = blockIdx.x * PTILE;
    int m = ne - e0; if (m > PTILE) m = PTILE;
    if (m <= 0) return;
    int t = threadIdx.x;
    h[t] = 0;
    __syncthreads();
    for (int k = t; k < m; k += 512) atomicAdd(&h[dst[e0 + k] >> BKB], 1);
    __syncthreads();
    int hv = h[t];
    sc[t] = hv;
    __syncthreads();
    for (int off = 1; off < 512; off <<= 1) {
        int u = (t >= off) ? sc[t - off] : 0;
        __syncthreads();
        sc[t] += u;
        __syncthreads();
    }
    base[t] = hv ? atomicAdd(&bcur[t], hv) : 0;
    lcur[t] = 0;
    __syncthreads();
    for (int k = t; k < m; k += 512) {
        int d = dst[e0 + k];
        int b = d >> BKB;
        int r = atomicAdd(&lcur[b], 1);
        int slot = sc[b] - h[b] + r;              // tile-local bucket run
        sval[slot] = ((unsigned int)src[e0 + k] << BKB) | (unsigned int)(d & (BKS - 1));
        saddr[slot] = base[b] + r;                // global dest (bucket-grouped)
    }
    __syncthreads();
    for (int k = t; k < m; k += 512) ebuf[saddr[k]] = sval[k];
}

// ------------------- per-bucket CSR build in LDS: cnt, row_start, csr_src out
// 512 threads (8 waves/block) for latency hiding; hist/scan over 256 bins guarded.
__global__ __launch_bounds__(512) void k_csr(const int* __restrict__ bbase,
                                             const int* __restrict__ bcnt,
                                             const unsigned int* __restrict__ ebuf,
                                             int* __restrict__ cnt,
                                             int* __restrict__ row_start,
                                             int* __restrict__ csr_src, int n) {
    __shared__ int h[256], sc[256], lc[256];
    __shared__ int stage[MAXBE];
    int bk = blockIdx.x;
    int node0 = bk << BKB;
    int ebase = bbase[bk];
    int ecnt = bcnt[bk];
    int t = threadIdx.x;
    if (t < 256) { h[t] = 0; lc[t] = 0; }
    __syncthreads();
    for (int k = t; k < ecnt; k += 512) atomicAdd(&h[ebuf[ebase + k] & (BKS - 1)], 1);
    __syncthreads();
    int hv = (t < 256) ? h[t] : 0;
    if (t < 256) sc[t] = hv;
    __syncthreads();
    for (int off = 1; off < 256; off <<= 1) {
        int u = (t >= off && t < 256) ? sc[t - off] : 0;
        __syncthreads();
        if (t < 256) sc[t] += u;
        __syncthreads();
    }
    if (t < 256) {
        int node = node0 + t;
        if (node < n) { cnt[node] = hv; row_start[node] = ebase + sc[t] - hv; }
    }
    if (ecnt <= MAXBE) {
        for (int k = t; k < ecnt; k += 512) {
            unsigned int p = ebuf[ebase + k];
            int dl = p & (BKS - 1);
            int r = atomicAdd(&lc[dl], 1);
            stage[sc[dl] - h[dl] + r] = (int)(p >> BKB);
        }
        __syncthreads();
        for (int k = t; k < ecnt; k += 512) csr_src[ebase + k] = stage[k];
    } else {  // overflow fallback (never taken for this input)
        for (int k = t; k < ecnt; k += 512) {
            unsigned int p = ebuf[ebase + k];
            int dl = p & (BKS - 1);
            int r = atomicAdd(&lc[dl], 1);
            csr_src[ebase + sc[dl] - h[dl] + r] = (int)(p >> BKB);
        }
    }
}

// ------------------------------------------------- layer1 projection: X @ W1
// W1 read with wave-uniform float4 indices -> s_load broadcast (scalar pipe).
// unroll 4 keeps 4 streaming X float4-loads in flight.
__device__ __forceinline__ void fmaq(float4& a, float s, float4 w) {
    a.x = fmaf(s, w.x, a.x);
    a.y = fmaf(s, w.y, a.y);
    a.z = fmaf(s, w.z, a.z);
    a.w = fmaf(s, w.w, a.w);
}

__global__ __launch_bounds__(256) void k_proj1(const float* __restrict__ X,
                                               const float* __restrict__ W1,
                                               const int* __restrict__ cnt,
                                               float* __restrict__ hs1, int n) {
    int i = blockIdx.x * 256 + threadIdx.x;
    if (i >= n) return;

    const float4* __restrict__ xr = (const float4*)(X + (size_t)i * IDIM);
    const float4* __restrict__ W4 = (const float4*)W1;  // row k = W4[k*4 .. k*4+3]
    float4 a0 = make_float4(0.f, 0.f, 0.f, 0.f), a1 = a0, a2 = a0, a3 = a0;

#pragma unroll 4
    for (int k4 = 0; k4 < IDIM / 4; ++k4) {
        float4 x = xr[k4];
        const float4* w = W4 + k4 * 16;   // 4 rows x 4 float4, wave-uniform address
        fmaq(a0, x.x, w[0]);  fmaq(a1, x.x, w[1]);  fmaq(a2, x.x, w[2]);  fmaq(a3, x.x, w[3]);
        fmaq(a0, x.y, w[4]);  fmaq(a1, x.y, w[5]);  fmaq(a2, x.y, w[6]);  fmaq(a3, x.y, w[7]);
        fmaq(a0, x.z, w[8]);  fmaq(a1, x.z, w[9]);  fmaq(a2, x.z, w[10]); fmaq(a3, x.z, w[11]);
        fmaq(a0, x.w, w[12]); fmaq(a1, x.w, w[13]); fmaq(a2, x.w, w[14]); fmaq(a3, x.w, w[15]);
    }

    float di = rsqrtf((float)(cnt[i] + 1));
    a0.x *= di; a0.y *= di; a0.z *= di; a0.w *= di;
    a1.x *= di; a1.y *= di; a1.z *= di; a1.w *= di;
    a2.x *= di; a2.y *= di; a2.z *= di; a2.w *= di;
    a3.x *= di; a3.y *= di; a3.z *= di; a3.w *= di;
    float4* h4 = (float4*)(hs1 + (size_t)i * HID);
    h4[0] = a0; h4[1] = a1; h4[2] = a2; h4[3] = a3;
}

// ------------------------------------------- atomic-free aggregation via CSR
// 8 independent gathers in flight per iteration, 2 accumulator chains.
__device__ __forceinline__ void acc4(float4& a, float4 v) {
    a.x += v.x; a.y += v.y; a.z += v.z; a.w += v.w;
}

__device__ __forceinline__ float4 gacc(int rs, int c, int q,
                                       const int* __restrict__ csr_src,
                                       const float4* __restrict__ h4,
                                       float4 acc) {
    float4 acc2 = make_float4(0.f, 0.f, 0.f, 0.f);
    int k = 0;
    int head = (-rs) & 3;            // peel to 16B-aligned csr_src
    if (head > c) head = c;
    for (; k < head; ++k)
        acc4(acc, h4[(size_t)csr_src[rs + k] * 4 + q]);
    for (; k + 7 < c; k += 8) {
        int4 s0 = *(const int4*)(csr_src + rs + k);
        int4 s1 = *(const int4*)(csr_src + rs + k + 4);
        float4 v0 = h4[(size_t)s0.x * 4 + q];
        float4 v1 = h4[(size_t)s0.y * 4 + q];
        float4 v2 = h4[(size_t)s0.z * 4 + q];
        float4 v3 = h4[(size_t)s0.w * 4 + q];
        float4 w0 = h4[(size_t)s1.x * 4 + q];
        float4 w1 = h4[(size_t)s1.y * 4 + q];
        float4 w2 = h4[(size_t)s1.z * 4 + q];
        float4 w3 = h4[(size_t)s1.w * 4 + q];
        acc4(acc, v0);  acc4(acc2, w0);
        acc4(acc, v1);  acc4(acc2, w1);
        acc4(acc, v2);  acc4(acc2, w2);
        acc4(acc, v3);  acc4(acc2, w3);
    }
    for (; k + 3 < c; k += 4) {
        int4 s = *(const int4*)(csr_src + rs + k);
        acc4(acc, h4[(size_t)s.x * 4 + q]);
        acc4(acc2, h4[(size_t)s.y * 4 + q]);
        acc4(acc, h4[(size_t)s.z * 4 + q]);
        acc4(acc2, h4[(size_t)s.w * 4 + q]);
    }
    for (; k < c; ++k)
        acc4(acc, h4[(size_t)csr_src[rs + k] * 4 + q]);
    acc4(acc, acc2);
    return acc;
}

// gather + fused layer-1 finalize: h2 = relu(di*agg + b1) * di
__global__ __launch_bounds__(256) void k_gather_mid(const int* __restrict__ row_start,
                                                    const int* __restrict__ cnt,
                                                    const int* __restrict__ csr_src,
                                                    const float* __restrict__ hs,
                                                    const float* __restrict__ b1,
                                                    float* __restrict__ outbuf, int n) {
    int tid = blockIdx.x * blockDim.x + threadIdx.x;
    int i = tid >> 2;
    int q = tid & 3;
    if (i >= n) return;
    const float4* h4 = (const float4*)hs;
    int rs = row_start[i];
    int c = cnt[i];
    float4 acc = gacc(rs, c, q, csr_src, h4, h4[(size_t)i * 4 + q]);  // self loop as init
    float di = rsqrtf((float)(c + 1));
    float4 b = ((const float4*)b1)[q];
    float4 r;
    r.x = fmaxf(fmaf(di, acc.x, b.x), 0.f) * di;
    r.y = fmaxf(fmaf(di, acc.y, b.y), 0.f) * di;
    r.z = fmaxf(fmaf(di, acc.z, b.z), 0.f) * di;
    r.w = fmaxf(fmaf(di, acc.w, b.w), 0.f) * di;
    ((float4*)outbuf)[(size_t)i * 4 + q] = r;
}

// plain gather (layer 2 aggregation)
__global__ __launch_bounds__(256) void k_gather(const int* __restrict__ row_start,
                                                const int* __restrict__ cnt,
                                                const int* __restrict__ csr_src,
                                                const float* __restrict__ hs,
                                                float* __restrict__ agg, int n) {
    int tid = blockIdx.x * blockDim.x + threadIdx.x;
    int i = tid >> 2;
    int q = tid & 3;
    if (i >= n) return;
    const float4* h4 = (const float4*)hs;
    int rs = row_start[i];
    int c = cnt[i];
    float4 acc = gacc(rs, c, q, csr_src, h4, h4[(size_t)i * 4 + q]);
    ((float4*)agg)[(size_t)i * 4 + q] = acc;
}

// ----------------------------------------------- output projection g @ W2 + b
// Each thread owns ONE W2 column (16 VGPRs), amortized over 4 nodes.
__global__ __launch_bounds__(256) void k_out(const int* __restrict__ cnt,
                                             const float* __restrict__ agg2,
                                             const float* __restrict__ W2,
                                             const float* __restrict__ b2,
                                             float* __restrict__ out, int n) {
    __shared__ float Ws[HID * ODIM];
    __shared__ float bs[ODIM];
    int t = threadIdx.x;
    for (int u = t; u < HID * ODIM; u += 256) Ws[u] = W2[u];
    if (t < ODIM) bs[t] = b2[t];
    __syncthreads();

    int j = t & 63;            // output column
    int slot = t >> 6;         // 0..3 (== wave id)
    int i0 = blockIdx.x * 16 + slot * 4;

    float wc[HID];
#pragma unroll
    for (int k = 0; k < HID; ++k) wc[k] = Ws[k * ODIM + j];
    float bj = bs[j];

    const float4* g4 = (const float4*)agg2;
#pragma unroll
    for (int u = 0; u < 4; ++u) {
        int i = i0 + u;
        if (i < n) {
            float4 g0 = g4[(size_t)i * 4 + 0];
            float4 g1 = g4[(size_t)i * 4 + 1];
            float4 g2 = g4[(size_t)i * 4 + 2];
            float4 g3 = g4[(size_t)i * 4 + 3];
            float acc = g0.x * wc[0]  + g0.y * wc[1]  + g0.z * wc[2]  + g0.w * wc[3]
                      + g1.x * wc[4]  + g1.y * wc[5]  + g1.z * wc[6]  + g1.w * wc[7]
                      + g2.x * wc[8]  + g2.y * wc[9]  + g2.z * wc[10] + g2.w * wc[11]
                      + g3.x * wc[12] + g3.y * wc[13] + g3.z * wc[14] + g3.w * wc[15];
            float di = rsqrtf((float)(cnt[i] + 1));
            out[(size_t)i * ODIM + j] = fmaf(di, acc, bj);
        }
    }
}

// ---------------------------------------------------------------------- launch
extern "C" void kernel_launch(void* const* d_in, const int* in_sizes, int n_in,
                              void* d_out, int out_size, void* d_ws, size_t ws_size,
                              hipStream_t stream) {
    const int* E = (const int*)d_in[1];
    const float* X = (const float*)d_in[2];
    const float* W1 = (const float*)d_in[3];
    const float* b1 = (const float*)d_in[4];
    const float* W2 = (const float*)d_in[5];
    const float* b2 = (const float*)d_in[6];
    float* out = (float*)d_out;

    const int n = in_sizes[0];       // 100000
    const int ne = in_sizes[1] / 2;  // 3200000
    const int* src = E;
    const int* dst = E + ne;
    const int nbk = (n + BKS - 1) >> BKB;  // 391

    // workspace layout (bytes):
    //   bcnt      @ 0     (2 KB)
    //   bbase     @ 8 KB
    //   bcur      @ 16 KB
    //   cnt       @ 1 MB  (400 KB)
    //   row_start @ 2 MB  (400 KB)
    //   ebuf      @ 3 MB  (12.8 MB)  [dead after k_csr; B1/B2 alias it]
    //   B1        @ 3 MB  (6.4 MB)
    //   B2        @ 10 MB (6.4 MB)
    //   csr_src   @ 17 MB (12.8 MB)   -> total 29.8 MB
    char* ws = (char*)d_ws;
    int* bcnt = (int*)ws;
    int* bbase = (int*)(ws + (8u << 10));
    int* bcur = (int*)(ws + (16u << 10));
    int* cnt = (int*)(ws + (1u << 20));
    int* row_start = (int*)(ws + (2u << 20));
    unsigned int* ebuf = (unsigned int*)(ws + (3u << 20));
    float* B1 = (float*)(ws + (3u << 20));
    float* B2 = (float*)(ws + (10u << 20));
    int* csr_src = (int*)(ws + (17u << 20));

    hipMemsetAsync(bcnt, 0, nbk * sizeof(int), stream);
    k_bhist<<<1024, 256, 0, stream>>>(dst, bcnt, ne, nbk);
    k_bscan<<<1, 512, 0, stream>>>(bcnt, bbase, bcur, nbk);
    k_part<<<(ne + PTILE - 1) / PTILE, 512, 0, stream>>>(src, dst, bcur, ebuf, ne, nbk);
    k_csr<<<nbk, 512, 0, stream>>>(bbase, bcnt, ebuf, cnt, row_start, csr_src, n);

    k_proj1<<<(n + 255) / 256, 256, 0, stream>>>(X, W1, cnt, B1, n);
    k_gather_mid<<<(n * 4 + 255) / 256, 256, 0, stream>>>(row_start, cnt, csr_src, B1, b1, B2, n);
    k_gather<<<(n * 4 + 255) / 256, 256, 0, stream>>>(row_start, cnt, csr_src, B2, B1, n);
    k_out<<<(n + 15) / 16, 256, 0, stream>>>(cnt, B1, W2, b2, out, n);
}

// Round 4
// 498.669 us; speedup vs baseline: 1.6992x; 1.0216x over previous
//
#include <hip/hip_runtime.h>

#define HID 16
#define ODIM 64
#define IDIM 512
#define BKB 8          // bucket = 256 nodes (dst >> 8)
#define BKS 256
#define PTILE 8192     // edges per partition tile
#define PITER 16       // PTILE / 512
#define PAD 16         // ints per padded counter slot (64 B line)

// inclusive block scan (blockDim.x == 512) via wave shuffles; 2 barriers total.
__device__ __forceinline__ int wave_scan_block(int v, int t, int* wsum) {
    int lane = t & 63, w = t >> 6;
    int x = v;
#pragma unroll
    for (int off = 1; off < 64; off <<= 1) {
        int y = __shfl_up(x, off, 64);
        if (lane >= off) x += y;
    }
    if (lane == 63) wsum[w] = x;
    __syncthreads();
    if (w == 0) {
        int s = (lane < 8) ? wsum[lane] : 0;
#pragma unroll
        for (int off = 1; off < 8; off <<= 1) {
            int y = __shfl_up(s, off, 64);
            if (lane >= off) s += y;
        }
        if (lane < 8) wsum[lane] = s;
    }
    __syncthreads();
    return x + (w ? wsum[w - 1] : 0);
}

// ---------------------------------------------------- bucket histogram (dst>>8)
// 256 blocks x 512 thr: per-block LDS hist -> only 100k padded global atomics.
__global__ __launch_bounds__(512) void k_bhist(const int* __restrict__ dst,
                                               int* __restrict__ bcnt, int ne, int nbk) {
    __shared__ int h[512];
    int t = threadIdx.x;
    h[t] = 0;
    __syncthreads();
    int stride = gridDim.x * 512;
    for (int e = blockIdx.x * 512 + t; e < ne; e += stride)
        atomicAdd(&h[dst[e] >> BKB], 1);
    __syncthreads();
    if (t < nbk && h[t]) atomicAdd(&bcnt[t * PAD], h[t]);
}

// ------------------------------------------------- scan bucket counts (wave scan)
__global__ __launch_bounds__(512) void k_bscan(const int* __restrict__ bcnt,
                                               int* __restrict__ bbase,
                                               int* __restrict__ bcur, int nbk) {
    __shared__ int wsum[8];
    int t = threadIdx.x;
    int v = (t < nbk) ? bcnt[t * PAD] : 0;
    int inc = wave_scan_block(v, t, wsum);
    if (t < nbk) { int b = inc - v; bbase[t] = b; bcur[t * PAD] = b; }
}

// ------------------------------------- partition edges into buckets (staged LDS)
// packed entry: (src << 8) | (dst & 255);  src < 2^17 so fits u32.
// dst tile stashed in registers (static unroll) -> single global read of dst.
__global__ __launch_bounds__(512) void k_part(const int* __restrict__ src,
                                              const int* __restrict__ dst,
                                              int* __restrict__ bcur,
                                              unsigned int* __restrict__ ebuf, int ne) {
    __shared__ int h[512], sc[512], base[512], lcur[512], wsum[8];
    __shared__ unsigned int sval[PTILE];
    __shared__ int saddr[PTILE];
    int e0 = blockIdx.x * PTILE;
    int m = ne - e0; if (m > PTILE) m = PTILE;
    int t = threadIdx.x;
    h[t] = 0;
    __syncthreads();
    int dv[PITER];
#pragma unroll
    for (int it = 0; it < PITER; ++it) {
        int k = t + it * 512;
        int d = 0;
        if (k < m) { d = dst[e0 + k]; atomicAdd(&h[d >> BKB], 1); }
        dv[it] = d;
    }
    __syncthreads();
    int hv = h[t];
    int inc = wave_scan_block(hv, t, wsum);
    sc[t] = inc;
    base[t] = hv ? atomicAdd(&bcur[t * PAD], hv) : 0;
    lcur[t] = 0;
    __syncthreads();
#pragma unroll
    for (int it = 0; it < PITER; ++it) {
        int k = t + it * 512;
        if (k < m) {
            int d = dv[it];
            int b = d >> BKB;
            int r = atomicAdd(&lcur[b], 1);
            int slot = sc[b] - h[b] + r;              // tile-local bucket run
            sval[slot] = ((unsigned int)src[e0 + k] << BKB) | (unsigned int)(d & (BKS - 1));
            saddr[slot] = base[b] + r;                // global dest (bucket-grouped)
        }
    }
    __syncthreads();
#pragma unroll
    for (int it = 0; it < PITER; ++it) {
        int k = t + it * 512;
        if (k < m) ebuf[saddr[k]] = sval[k];
    }
}

// ------------------- per-bucket CSR build: cnt, row_start, csr_src (direct scatter)
// Block's csr_src region is a contiguous ~32KB -> stays hot in its XCD L2;
// random 4B stores within it write-combine fully (no HBM amplification).
__global__ __launch_bounds__(512) void k_csr(const int* __restrict__ bbase,
                                             const int* __restrict__ bcnt,
                                             const unsigned int* __restrict__ ebuf,
                                             int* __restrict__ cnt,
                                             int* __restrict__ row_start,
                                             int* __restrict__ csr_src, int n) {
    __shared__ int h[256], sc[256], lc[256], wsum[8];
    int bk = blockIdx.x;
    int node0 = bk << BKB;
    int ebase = bbase[bk];
    int ecnt = bcnt[bk * PAD];
    int t = threadIdx.x;
    if (t < 256) { h[t] = 0; lc[t] = 0; }
    __syncthreads();
    for (int k = t; k < ecnt; k += 512) atomicAdd(&h[ebuf[ebase + k] & (BKS - 1)], 1);
    __syncthreads();
    int hv = (t < 256) ? h[t] : 0;
    int inc = wave_scan_block(hv, t, wsum);
    if (t < 256) {
        sc[t] = inc;
        int node = node0 + t;
        if (node < n) { cnt[node] = hv; row_start[node] = ebase + inc - hv; }
    }
    __syncthreads();
    for (int k = t; k < ecnt; k += 512) {
        unsigned int p = ebuf[ebase + k];
        int dl = p & (BKS - 1);
        int r = atomicAdd(&lc[dl], 1);
        csr_src[ebase + sc[dl] - h[dl] + r] = (int)(p >> BKB);
    }
}

// ------------------------------------------------- layer1 projection: X @ W1
// W1 read with wave-uniform float4 indices -> s_load broadcast (scalar pipe).
__device__ __forceinline__ void fmaq(float4& a, float s, float4 w) {
    a.x = fmaf(s, w.x, a.x);
    a.y = fmaf(s, w.y, a.y);
    a.z = fmaf(s, w.z, a.z);
    a.w = fmaf(s, w.w, a.w);
}

__global__ __launch_bounds__(256) void k_proj1(const float* __restrict__ X,
                                               const float* __restrict__ W1,
                                               const int* __restrict__ cnt,
                                               float* __restrict__ hs1, int n) {
    int i = blockIdx.x * 256 + threadIdx.x;
    if (i >= n) return;

    const float4* __restrict__ xr = (const float4*)(X + (size_t)i * IDIM);
    const float4* __restrict__ W4 = (const float4*)W1;  // row k = W4[k*4 .. k*4+3]
    float4 a0 = make_float4(0.f, 0.f, 0.f, 0.f), a1 = a0, a2 = a0, a3 = a0;

#pragma unroll 4
    for (int k4 = 0; k4 < IDIM / 4; ++k4) {
        float4 x = xr[k4];
        const float4* w = W4 + k4 * 16;   // 4 rows x 4 float4, wave-uniform address
        fmaq(a0, x.x, w[0]);  fmaq(a1, x.x, w[1]);  fmaq(a2, x.x, w[2]);  fmaq(a3, x.x, w[3]);
        fmaq(a0, x.y, w[4]);  fmaq(a1, x.y, w[5]);  fmaq(a2, x.y, w[6]);  fmaq(a3, x.y, w[7]);
        fmaq(a0, x.z, w[8]);  fmaq(a1, x.z, w[9]);  fmaq(a2, x.z, w[10]); fmaq(a3, x.z, w[11]);
        fmaq(a0, x.w, w[12]); fmaq(a1, x.w, w[13]); fmaq(a2, x.w, w[14]); fmaq(a3, x.w, w[15]);
    }

    float di = rsqrtf((float)(cnt[i] + 1));
    a0.x *= di; a0.y *= di; a0.z *= di; a0.w *= di;
    a1.x *= di; a1.y *= di; a1.z *= di; a1.w *= di;
    a2.x *= di; a2.y *= di; a2.z *= di; a2.w *= di;
    a3.x *= di; a3.y *= di; a3.z *= di; a3.w *= di;
    float4* h4 = (float4*)(hs1 + (size_t)i * HID);
    h4[0] = a0; h4[1] = a1; h4[2] = a2; h4[3] = a3;
}

// ------------------------------------------- atomic-free aggregation via CSR
// 8 independent gathers in flight per iteration, 2 accumulator chains.
__device__ __forceinline__ void acc4(float4& a, float4 v) {
    a.x += v.x; a.y += v.y; a.z += v.z; a.w += v.w;
}

__device__ __forceinline__ float4 gacc(int rs, int c, int q,
                                       const int* __restrict__ csr_src,
                                       const float4* __restrict__ h4,
                                       float4 acc) {
    float4 acc2 = make_float4(0.f, 0.f, 0.f, 0.f);
    int k = 0;
    int head = (-rs) & 3;            // peel to 16B-aligned csr_src
    if (head > c) head = c;
    for (; k < head; ++k)
        acc4(acc, h4[(size_t)csr_src[rs + k] * 4 + q]);
    for (; k + 7 < c; k += 8) {
        int4 s0 = *(const int4*)(csr_src + rs + k);
        int4 s1 = *(const int4*)(csr_src + rs + k + 4);
        float4 v0 = h4[(size_t)s0.x * 4 + q];
        float4 v1 = h4[(size_t)s0.y * 4 + q];
        float4 v2 = h4[(size_t)s0.z * 4 + q];
        float4 v3 = h4[(size_t)s0.w * 4 + q];
        float4 w0 = h4[(size_t)s1.x * 4 + q];
        float4 w1 = h4[(size_t)s1.y * 4 + q];
        float4 w2 = h4[(size_t)s1.z * 4 + q];
        float4 w3 = h4[(size_t)s1.w * 4 + q];
        acc4(acc, v0);  acc4(acc2, w0);
        acc4(acc, v1);  acc4(acc2, w1);
        acc4(acc, v2);  acc4(acc2, w2);
        acc4(acc, v3);  acc4(acc2, w3);
    }
    for (; k + 3 < c; k += 4) {
        int4 s = *(const int4*)(csr_src + rs + k);
        acc4(acc, h4[(size_t)s.x * 4 + q]);
        acc4(acc2, h4[(size_t)s.y * 4 + q]);
        acc4(acc, h4[(size_t)s.z * 4 + q]);
        acc4(acc2, h4[(size_t)s.w * 4 + q]);
    }
    for (; k < c; ++k)
        acc4(acc, h4[(size_t)csr_src[rs + k] * 4 + q]);
    acc4(acc, acc2);
    return acc;
}

// gather + fused layer-1 finalize: h2 = relu(di*agg + b1) * di
__global__ __launch_bounds__(256) void k_gather_mid(const int* __restrict__ row_start,
                                                    const int* __restrict__ cnt,
                                                    const int* __restrict__ csr_src,
                                                    const float* __restrict__ hs,
                                                    const float* __restrict__ b1,
                                                    float* __restrict__ outbuf, int n) {
    int tid = blockIdx.x * blockDim.x + threadIdx.x;
    int i = tid >> 2;
    int q = tid & 3;
    if (i >= n) return;
    const float4* h4 = (const float4*)hs;
    int rs = row_start[i];
    int c = cnt[i];
    float4 acc = gacc(rs, c, q, csr_src, h4, h4[(size_t)i * 4 + q]);  // self loop as init
    float di = rsqrtf((float)(c + 1));
    float4 b = ((const float4*)b1)[q];
    float4 r;
    r.x = fmaxf(fmaf(di, acc.x, b.x), 0.f) * di;
    r.y = fmaxf(fmaf(di, acc.y, b.y), 0.f) * di;
    r.z = fmaxf(fmaf(di, acc.z, b.z), 0.f) * di;
    r.w = fmaxf(fmaf(di, acc.w, b.w), 0.f) * di;
    ((float4*)outbuf)[(size_t)i * 4 + q] = r;
}

// plain gather (layer 2 aggregation)
__global__ __launch_bounds__(256) void k_gather(const int* __restrict__ row_start,
                                                const int* __restrict__ cnt,
                                                const int* __restrict__ csr_src,
                                                const float* __restrict__ hs,
                                                float* __restrict__ agg, int n) {
    int tid = blockIdx.x * blockDim.x + threadIdx.x;
    int i = tid >> 2;
    int q = tid & 3;
    if (i >= n) return;
    const float4* h4 = (const float4*)hs;
    int rs = row_start[i];
    int c = cnt[i];
    float4 acc = gacc(rs, c, q, csr_src, h4, h4[(size_t)i * 4 + q]);
    ((float4*)agg)[(size_t)i * 4 + q] = acc;
}

// ----------------------------------------------- output projection g @ W2 + b
// Each thread owns ONE W2 column (16 VGPRs), amortized over 4 nodes.
__global__ __launch_bounds__(256) void k_out(const int* __restrict__ cnt,
                                             const float* __restrict__ agg2,
                                             const float* __restrict__ W2,
                                             const float* __restrict__ b2,
                                             float* __restrict__ out, int n) {
    __shared__ float Ws[HID * ODIM];
    __shared__ float bs[ODIM];
    int t = threadIdx.x;
    for (int u = t; u < HID * ODIM; u += 256) Ws[u] = W2[u];
    if (t < ODIM) bs[t] = b2[t];
    __syncthreads();

    int j = t & 63;            // output column
    int slot = t >> 6;         // 0..3 (== wave id)
    int i0 = blockIdx.x * 16 + slot * 4;

    float wc[HID];
#pragma unroll
    for (int k = 0; k < HID; ++k) wc[k] = Ws[k * ODIM + j];
    float bj = bs[j];

    const float4* g4 = (const float4*)agg2;
#pragma unroll
    for (int u = 0; u < 4; ++u) {
        int i = i0 + u;
        if (i < n) {
            float4 g0 = g4[(size_t)i * 4 + 0];
            float4 g1 = g4[(size_t)i * 4 + 1];
            float4 g2 = g4[(size_t)i * 4 + 2];
            float4 g3 = g4[(size_t)i * 4 + 3];
            float acc = g0.x * wc[0]  + g0.y * wc[1]  + g0.z * wc[2]  + g0.w * wc[3]
                      + g1.x * wc[4]  + g1.y * wc[5]  + g1.z * wc[6]  + g1.w * wc[7]
                      + g2.x * wc[8]  + g2.y * wc[9]  + g2.z * wc[10] + g2.w * wc[11]
                      + g3.x * wc[12] + g3.y * wc[13] + g3.z * wc[14] + g3.w * wc[15];
            float di = rsqrtf((float)(cnt[i] + 1));
            out[(size_t)i * ODIM + j] = fmaf(di, acc, bj);
        }
    }
}

// ---------------------------------------------------------------------- launch
extern "C" void kernel_launch(void* const* d_in, const int* in_sizes, int n_in,
                              void* d_out, int out_size, void* d_ws, size_t ws_size,
                              hipStream_t stream) {
    const int* E = (const int*)d_in[1];
    const float* X = (const float*)d_in[2];
    const float* W1 = (const float*)d_in[3];
    const float* b1 = (const float*)d_in[4];
    const float* W2 = (const float*)d_in[5];
    const float* b2 = (const float*)d_in[6];
    float* out = (float*)d_out;

    const int n = in_sizes[0];       // 100000
    const int ne = in_sizes[1] / 2;  // 3200000
    const int* src = E;
    const int* dst = E + ne;
    const int nbk = (n + BKS - 1) >> BKB;  // 391

    // workspace layout (bytes):
    //   bcnt(pad) @ 0     (25 KB)
    //   bbase     @ 32 KB (2 KB)
    //   bcur(pad) @ 64 KB (25 KB)
    //   cnt       @ 1 MB  (400 KB)
    //   row_start @ 2 MB  (400 KB)
    //   ebuf      @ 3 MB  (12.8 MB)  [dead after k_csr; B1/B2 alias it]
    //   B1        @ 3 MB  (6.4 MB)
    //   B2        @ 10 MB (6.4 MB)
    //   csr_src   @ 17 MB (12.8 MB)   -> total 29.8 MB
    char* ws = (char*)d_ws;
    int* bcnt = (int*)ws;
    int* bbase = (int*)(ws + (32u << 10));
    int* bcur = (int*)(ws + (64u << 10));
    int* cnt = (int*)(ws + (1u << 20));
    int* row_start = (int*)(ws + (2u << 20));
    unsigned int* ebuf = (unsigned int*)(ws + (3u << 20));
    float* B1 = (float*)(ws + (3u << 20));
    float* B2 = (float*)(ws + (10u << 20));
    int* csr_src = (int*)(ws + (17u << 20));

    hipMemsetAsync(bcnt, 0, nbk * PAD * sizeof(int), stream);
    k_bhist<<<256, 512, 0, stream>>>(dst, bcnt, ne, nbk);
    k_bscan<<<1, 512, 0, stream>>>(bcnt, bbase, bcur, nbk);
    k_part<<<(ne + PTILE - 1) / PTILE, 512, 0, stream>>>(src, dst, bcur, ebuf, ne);
    k_csr<<<nbk, 512, 0, stream>>>(bbase, bcnt, ebuf, cnt, row_start, csr_src, n);

    k_proj1<<<(n + 255) / 256, 256, 0, stream>>>(X, W1, cnt, B1, n);
    k_gather_mid<<<(n * 4 + 255) / 256, 256, 0, stream>>>(row_start, cnt, csr_src, B1, b1, B2, n);
    k_gather<<<(n * 4 + 255) / 256, 256, 0, stream>>>(row_start, cnt, csr_src, B2, B1, n);
    k_out<<<(n + 15) / 16, 256, 0, stream>>>(cnt, B1, W2, b2, out, n);
}